// Round 3
// baseline (432.708 us; speedup 1.0000x reference)
//
#include <hip/hip_runtime.h>

// Problem constants
#define BB 4
#define SS 2048
#define DD 1024   // DIM_IN = DIM_Q = DIM_V = 1024

typedef __attribute__((ext_vector_type(8))) short short8;
typedef __attribute__((ext_vector_type(4))) float f32x4;

__device__ __forceinline__ unsigned short f2b(float f) {
  unsigned u = __builtin_bit_cast(unsigned, f);
  u += 0x7fffu + ((u >> 16) & 1u);   // RNE
  return (unsigned short)(u >> 16);
}

__device__ __forceinline__ void gl2lds16(const void* g, void* l) {
  __builtin_amdgcn_global_load_lds(
      (__attribute__((address_space(1))) unsigned int*)(void*)(size_t)(uintptr_t)g,
      (__attribute__((address_space(3))) unsigned int*)l, 16, 0, 0);
}

// ------------- mask dtype probe: int32 (0/1 words) vs uint8 (packed bools) --
// If bytes are packed random bools, an int32 view shows values >1 w.p. 7/8
// per word; P(false "i32" verdict over 1024 words) = (1/8)^1024 ~ 0.
__global__ void detect_mask(const unsigned int* __restrict__ m, int* __restrict__ flag) {
  unsigned any = 0;
#pragma unroll
  for (int i = 0; i < 16; ++i) {
    unsigned v = m[threadIdx.x * 16 + i];
    any |= (v > 1u) ? 1u : 0u;
  }
  unsigned long long b = __ballot(any != 0u);
  if (threadIdx.x == 0) *flag = (b != 0ULL) ? 1 : 0;  // 1 => uint8 layout
}

// ---------------- fp32 -> bf16 convert, z picks one of 3 tensors ----------
__global__ __launch_bounds__(256) void cvt3(
    const float* __restrict__ s0, const float* __restrict__ s1, const float* __restrict__ s2,
    unsigned short* __restrict__ d0, unsigned short* __restrict__ d1, unsigned short* __restrict__ d2) {
  const float* s = blockIdx.z == 0 ? s0 : (blockIdx.z == 1 ? s1 : s2);
  unsigned short* d = blockIdx.z == 0 ? d0 : (blockIdx.z == 1 ? d1 : d2);
  size_t i = ((size_t)blockIdx.x * 256 + threadIdx.x) * 8;
  float4 a = *(const float4*)(s + i);
  float4 b = *(const float4*)(s + i + 4);
  union { unsigned short us[8]; uint4 v; } o;
  o.us[0] = f2b(a.x); o.us[1] = f2b(a.y); o.us[2] = f2b(a.z); o.us[3] = f2b(a.w);
  o.us[4] = f2b(b.x); o.us[5] = f2b(b.y); o.us[6] = f2b(b.z); o.us[7] = f2b(b.w);
  *(uint4*)(d + i) = o.v;
}

// ---------------- BT-layout bf16 GEMM: C[m][n] = sum_k A[m][k]*B[n][k] -----
// 128x128 tile, BK=32, 256 threads (4 waves, each 64x64 via 4x4 MFMA 16x16x32)
enum { EPI_BIAS_COL = 0, EPI_BIAS_ROW = 1, EPI_MASK = 2, EPI_OUT = 3 };

template <int EPI>
__global__ __launch_bounds__(256, 2) void gemm_bt(
    const unsigned short* __restrict__ A, int lda, long long aBatch,
    const unsigned short* __restrict__ Bm, int ldb, long long bBatch,
    void* __restrict__ Cv, int ldc, long long cBatch,
    int K,
    const float* __restrict__ bias,
    const void* __restrict__ mask, long long maskBatch,
    const int* __restrict__ mflag,
    float scale) {
  __shared__ unsigned short sA[128 * 32];
  __shared__ unsigned short sB[128 * 32];
  const int tid  = threadIdx.x;
  const int wave = tid >> 6;
  const int lane = tid & 63;
  const int l15  = lane & 15;
  const int quad = lane >> 4;
  const int waveR = wave >> 1, waveC = wave & 1;
  const int bm = blockIdx.x * 128;
  const int bn = blockIdx.y * 128;
  const int z  = blockIdx.z;
  A  += (long long)z * aBatch;
  Bm += (long long)z * bBatch;

  const unsigned short* gA0 = A  + (size_t)(bm + (tid >> 2)) * lda + (tid & 3) * 8;
  const unsigned short* gA1 = gA0 + (size_t)64 * lda;
  const unsigned short* gB0 = Bm + (size_t)(bn + (tid >> 2)) * ldb + (tid & 3) * 8;
  const unsigned short* gB1 = gB0 + (size_t)64 * ldb;
  unsigned short* lA = sA + wave * 64 * 8;   // wave-uniform LDS base; HW adds lane*16B
  unsigned short* lB = sB + wave * 64 * 8;

  f32x4 acc[4][4] = {};

  const int aro = (waveR * 64 + l15) * 32 + quad * 8;
  const int bro = (waveC * 64 + l15) * 32 + quad * 8;

  for (int kt = 0; kt < K; kt += 32) {
    gl2lds16(gA0, lA);
    gl2lds16(gA1, lA + 256 * 8);
    gl2lds16(gB0, lB);
    gl2lds16(gB1, lB + 256 * 8);
    gA0 += 32; gA1 += 32; gB0 += 32; gB1 += 32;
    __syncthreads();
    short8 af[4], bf[4];
#pragma unroll
    for (int i = 0; i < 4; ++i) af[i] = *(const short8*)(sA + aro + i * 16 * 32);
#pragma unroll
    for (int j = 0; j < 4; ++j) bf[j] = *(const short8*)(sB + bro + j * 16 * 32);
#pragma unroll
    for (int i = 0; i < 4; ++i)
#pragma unroll
      for (int j = 0; j < 4; ++j)
        acc[i][j] = __builtin_amdgcn_mfma_f32_16x16x32_bf16(af[i], bf[j], acc[i][j], 0, 0, 0);
    __syncthreads();
  }

  // C/D layout: col = lane&15, row = quad*4 + reg
  const int r0 = bm + waveR * 64 + quad * 4;
  const int c0 = bn + waveC * 64 + l15;

  if constexpr (EPI == EPI_MASK) {
    float* Cz = (float*)Cv + (long long)z * cBatch;
    const int isU8 = *mflag;
    const unsigned char* m8 = (const unsigned char*)mask + (long long)z * maskBatch;
    const int* m32 = (const int*)mask + (long long)z * maskBatch;
#pragma unroll
    for (int i = 0; i < 4; ++i)
#pragma unroll
      for (int r = 0; r < 4; ++r) {
        int row = r0 + i * 16 + r;
#pragma unroll
        for (int j = 0; j < 4; ++j) {
          int col = c0 + j * 16;
          size_t idx = (size_t)row * ldc + col;
          float v = acc[i][j][r] * scale;
          int mv = isU8 ? (int)m8[idx] : m32[idx];
          if (mv) v = -1.0e9f;
          Cz[idx] = v;
        }
      }
  } else if constexpr (EPI == EPI_OUT) {
    float* Cz = (float*)Cv + (long long)z * cBatch;
#pragma unroll
    for (int i = 0; i < 4; ++i)
#pragma unroll
      for (int r = 0; r < 4; ++r) {
        int row = r0 + i * 16 + r;
#pragma unroll
        for (int j = 0; j < 4; ++j) {
          int col = c0 + j * 16;
          Cz[(size_t)row * ldc + col] = acc[i][j][r];
        }
      }
  } else {
    unsigned short* Cz = (unsigned short*)Cv + (long long)z * cBatch;
#pragma unroll
    for (int i = 0; i < 4; ++i)
#pragma unroll
      for (int r = 0; r < 4; ++r) {
        int row = r0 + i * 16 + r;
#pragma unroll
        for (int j = 0; j < 4; ++j) {
          int col = c0 + j * 16;
          float v = acc[i][j][r] + (EPI == EPI_BIAS_COL ? bias[col] : bias[row]);
          Cz[(size_t)row * ldc + col] = f2b(v);
        }
      }
  }
}

// ---------------- row softmax: one block per row, fp32 in -> bf16 out ------
__global__ __launch_bounds__(256) void softmax_rows(const float* __restrict__ Sc,
                                                    unsigned short* __restrict__ P) {
  const size_t r = blockIdx.x;
  const float* src = Sc + r * SS;
  unsigned short* dst = P + r * SS;
  const int tid = threadIdx.x;
  const int wave = tid >> 6, lane = tid & 63;
  float4 x0 = *(const float4*)(src + tid * 8);
  float4 x1 = *(const float4*)(src + tid * 8 + 4);
  float xs[8] = {x0.x, x0.y, x0.z, x0.w, x1.x, x1.y, x1.z, x1.w};
  float mx = xs[0];
#pragma unroll
  for (int k = 1; k < 8; ++k) mx = fmaxf(mx, xs[k]);
#pragma unroll
  for (int o = 32; o; o >>= 1) mx = fmaxf(mx, __shfl_xor(mx, o));
  __shared__ float red[8];
  if (lane == 0) red[wave] = mx;
  __syncthreads();
  mx = fmaxf(fmaxf(red[0], red[1]), fmaxf(red[2], red[3]));
  float e[8], s = 0.f;
#pragma unroll
  for (int k = 0; k < 8; ++k) { e[k] = __expf(xs[k] - mx); s += e[k]; }
#pragma unroll
  for (int o = 32; o; o >>= 1) s += __shfl_xor(s, o);
  if (lane == 0) red[4 + wave] = s;
  __syncthreads();
  s = (red[4] + red[5]) + (red[6] + red[7]);
  float inv = 1.0f / s;
  union { unsigned short us[8]; uint4 v; } o;
#pragma unroll
  for (int k = 0; k < 8; ++k) o.us[k] = f2b(e[k] * inv);
  *(uint4*)(dst + tid * 8) = o.v;
}

extern "C" void kernel_launch(void* const* d_in, const int* in_sizes, int n_in,
                              void* d_out, int out_size, void* d_ws, size_t ws_size,
                              hipStream_t stream) {
  const float* query = (const float*)d_in[0];
  const float* key   = (const float*)d_in[1];
  const float* value = (const float*)d_in[2];
  const void*  mask  = d_in[3];                 // bool: u8 or i32, probed at runtime
  const float* Wq = (const float*)d_in[4];
  const float* bq = (const float*)d_in[5];
  const float* Wk = (const float*)d_in[6];
  const float* bk = (const float*)d_in[7];
  const float* Wv = (const float*)d_in[8];
  const float* bv = (const float*)d_in[9];
  float* out = (float*)d_out;

  char* ws = (char*)d_ws;
  const size_t MB = 1024 * 1024;
  unsigned short* qin = (unsigned short*)(ws + 0 * MB);    // 8192x1024 bf16, 16MB
  unsigned short* kin = (unsigned short*)(ws + 16 * MB);
  unsigned short* vin = (unsigned short*)(ws + 32 * MB);
  unsigned short* Wqb = (unsigned short*)(ws + 48 * MB);   // 1024x1024 bf16, 2MB
  unsigned short* Wkb = (unsigned short*)(ws + 50 * MB);
  unsigned short* Wvb = (unsigned short*)(ws + 52 * MB);
  unsigned short* qb  = (unsigned short*)(ws + 54 * MB);   // q proj bf16, 16MB
  unsigned short* kb  = (unsigned short*)(ws + 70 * MB);   // k proj
  unsigned short* vT  = (unsigned short*)(ws + 86 * MB);   // v^T [1024][8192] bf16
  float*          Sc  = (float*)(ws + 102 * MB);           // scores fp32, 64MB
  unsigned short* P   = (unsigned short*)(ws + 166 * MB);  // softmax bf16, 32MB
  int*          flag  = (int*)(ws + 198 * MB);             // mask dtype flag

  dim3 blk(256);

  detect_mask<<<dim3(1), dim3(64), 0, stream>>>((const unsigned int*)mask, flag);

  // fp32 -> bf16
  cvt3<<<dim3(4096, 1, 3), blk, 0, stream>>>(query, key, value, qin, kin, vin);
  cvt3<<<dim3(512, 1, 3), blk, 0, stream>>>(Wq, Wk, Wv, Wqb, Wkb, Wvb);

  // q = query @ Wq^T + bq ; k = key @ Wk^T + bk   (bf16 out)
  gemm_bt<EPI_BIAS_COL><<<dim3(64, 8, 1), blk, 0, stream>>>(
      qin, 1024, 0, Wqb, 1024, 0, qb, 1024, 0, 1024, bq, nullptr, 0, flag, 0.f);
  gemm_bt<EPI_BIAS_COL><<<dim3(64, 8, 1), blk, 0, stream>>>(
      kin, 1024, 0, Wkb, 1024, 0, kb, 1024, 0, 1024, bk, nullptr, 0, flag, 0.f);

  // v^T[n][m] = sum_d Wv[n,d] * value[m,d] + bv[n]  -> [1024][8192] bf16
  gemm_bt<EPI_BIAS_ROW><<<dim3(8, 64, 1), blk, 0, stream>>>(
      Wvb, 1024, 0, vin, 1024, 0, vT, 8192, 0, 1024, bv, nullptr, 0, flag, 0.f);

  // scores[b][m][n] = mask ? -1e9 : (q_m . k_n) / 32   (fp32)
  gemm_bt<EPI_MASK><<<dim3(16, 16, BB), blk, 0, stream>>>(
      qb, 1024, (long long)SS * 1024, kb, 1024, (long long)SS * 1024,
      Sc, SS, (long long)SS * SS, 1024, nullptr, mask, (long long)SS * SS, flag, 0.03125f);

  // P = softmax(scores) rows, bf16
  softmax_rows<<<dim3(BB * SS), blk, 0, stream>>>(Sc, P);

  // out[b][m][n] = sum_k P[m][k] * vT[n][k]   (fp32 out)
  gemm_bt<EPI_OUT><<<dim3(16, 8, BB), blk, 0, stream>>>(
      P, SS, (long long)SS * SS, vT, 8192, (long long)SS,
      out, 1024, (long long)SS * 1024, SS, nullptr, nullptr, 0, flag, 1.f);
}

// Round 4
// 397.721 us; speedup vs baseline: 1.0880x; 1.0880x over previous
//
#include <hip/hip_runtime.h>

// Problem constants
#define BB 4
#define SS 2048
#define DD 1024   // DIM_IN = DIM_Q = DIM_V = 1024

typedef __attribute__((ext_vector_type(8))) short short8;
typedef __attribute__((ext_vector_type(4))) float f32x4;

__device__ __forceinline__ unsigned short f2b(float f) {
  unsigned u = __builtin_bit_cast(unsigned, f);
  u += 0x7fffu + ((u >> 16) & 1u);   // RNE
  return (unsigned short)(u >> 16);
}
__device__ __forceinline__ float b2f(unsigned short us) {
  unsigned u = (unsigned)us << 16;
  return __builtin_bit_cast(float, u);
}

__device__ __forceinline__ void gl2lds16(const void* g, void* l) {
  __builtin_amdgcn_global_load_lds(
      (__attribute__((address_space(1))) unsigned int*)(void*)(size_t)(uintptr_t)g,
      (__attribute__((address_space(3))) unsigned int*)l, 16, 0, 0);
}

// ------------- mask dtype probe: int32 (0/1 words) vs uint8 (packed bools) --
__global__ void detect_mask(const unsigned int* __restrict__ m, int* __restrict__ flag) {
  unsigned any = 0;
#pragma unroll
  for (int i = 0; i < 16; ++i) {
    unsigned v = m[threadIdx.x * 16 + i];
    any |= (v > 1u) ? 1u : 0u;
  }
  unsigned long long b = __ballot(any != 0u);
  if (threadIdx.x == 0) *flag = (b != 0ULL) ? 1 : 0;  // 1 => uint8 layout
}

// ------------- mask -> bitmask pre-pass (coalesced). 1 block per row. ------
// thread t packs cols [t*8, t*8+8) into one byte at bits[row*256 + t].
__global__ __launch_bounds__(256) void pack_mask(const void* __restrict__ mask,
                                                 const int* __restrict__ flag,
                                                 unsigned char* __restrict__ bits) {
  const size_t row = blockIdx.x;
  const int t = threadIdx.x;
  unsigned byte = 0;
  if (*flag) {  // uint8 packed bools
    uint2 v = *(const uint2*)((const unsigned char*)mask + row * SS + t * 8);
#pragma unroll
    for (int j = 0; j < 4; ++j) {
      byte |= (((v.x >> (8 * j)) & 0xffu) ? 1u : 0u) << j;
      byte |= (((v.y >> (8 * j)) & 0xffu) ? 1u : 0u) << (j + 4);
    }
  } else {      // int32 bools
    const uint4* p = (const uint4*)((const int*)mask + row * SS + t * 8);
    uint4 a = p[0], b = p[1];
    byte = (a.x ? 1u : 0u) | ((a.y ? 1u : 0u) << 1) | ((a.z ? 1u : 0u) << 2) |
           ((a.w ? 1u : 0u) << 3) | ((b.x ? 1u : 0u) << 4) | ((b.y ? 1u : 0u) << 5) |
           ((b.z ? 1u : 0u) << 6) | ((b.w ? 1u : 0u) << 7);
  }
  bits[row * 256 + t] = (unsigned char)byte;
}

// ---------------- fp32 -> bf16 convert, z picks one of 3 tensors ----------
__global__ __launch_bounds__(256) void cvt3(
    const float* __restrict__ s0, const float* __restrict__ s1, const float* __restrict__ s2,
    unsigned short* __restrict__ d0, unsigned short* __restrict__ d1, unsigned short* __restrict__ d2) {
  const float* s = blockIdx.z == 0 ? s0 : (blockIdx.z == 1 ? s1 : s2);
  unsigned short* d = blockIdx.z == 0 ? d0 : (blockIdx.z == 1 ? d1 : d2);
  size_t i = ((size_t)blockIdx.x * 256 + threadIdx.x) * 8;
  float4 a = *(const float4*)(s + i);
  float4 b = *(const float4*)(s + i + 4);
  union { unsigned short us[8]; uint4 v; } o;
  o.us[0] = f2b(a.x); o.us[1] = f2b(a.y); o.us[2] = f2b(a.z); o.us[3] = f2b(a.w);
  o.us[4] = f2b(b.x); o.us[5] = f2b(b.y); o.us[6] = f2b(b.z); o.us[7] = f2b(b.w);
  *(uint4*)(d + i) = o.v;
}

// ---------------- BT-layout bf16 GEMM: C[m][n] = sum_k A[m][k]*B[n][k] -----
// 128x128 tile, BK=32, 256 threads (4 waves, each 64x64 via 4x4 MFMA 16x16x32)
enum { EPI_BIAS_COL = 0, EPI_BIAS_ROW = 1, EPI_SCORE = 2, EPI_OUT = 3 };

template <int EPI>
__global__ __launch_bounds__(256, 2) void gemm_bt(
    const unsigned short* __restrict__ A, int lda, long long aBatch,
    const unsigned short* __restrict__ Bm, int ldb, long long bBatch,
    void* __restrict__ Cv, int ldc, long long cBatch,
    int K,
    const float* __restrict__ bias,
    float scale) {
  __shared__ unsigned short sA[128 * 32];
  __shared__ unsigned short sB[128 * 32];
  const int tid  = threadIdx.x;
  const int wave = tid >> 6;
  const int lane = tid & 63;
  const int l15  = lane & 15;
  const int quad = lane >> 4;
  const int waveR = wave >> 1, waveC = wave & 1;
  const int bm = blockIdx.x * 128;
  const int bn = blockIdx.y * 128;
  const int z  = blockIdx.z;
  A  += (long long)z * aBatch;
  Bm += (long long)z * bBatch;

  const unsigned short* gA0 = A  + (size_t)(bm + (tid >> 2)) * lda + (tid & 3) * 8;
  const unsigned short* gA1 = gA0 + (size_t)64 * lda;
  const unsigned short* gB0 = Bm + (size_t)(bn + (tid >> 2)) * ldb + (tid & 3) * 8;
  const unsigned short* gB1 = gB0 + (size_t)64 * ldb;
  unsigned short* lA = sA + wave * 64 * 8;   // wave-uniform LDS base; HW adds lane*16B
  unsigned short* lB = sB + wave * 64 * 8;

  f32x4 acc[4][4] = {};

  const int aro = (waveR * 64 + l15) * 32 + quad * 8;
  const int bro = (waveC * 64 + l15) * 32 + quad * 8;

  for (int kt = 0; kt < K; kt += 32) {
    gl2lds16(gA0, lA);
    gl2lds16(gA1, lA + 256 * 8);
    gl2lds16(gB0, lB);
    gl2lds16(gB1, lB + 256 * 8);
    gA0 += 32; gA1 += 32; gB0 += 32; gB1 += 32;
    __syncthreads();
    short8 af[4], bf[4];
#pragma unroll
    for (int i = 0; i < 4; ++i) af[i] = *(const short8*)(sA + aro + i * 16 * 32);
#pragma unroll
    for (int j = 0; j < 4; ++j) bf[j] = *(const short8*)(sB + bro + j * 16 * 32);
#pragma unroll
    for (int i = 0; i < 4; ++i)
#pragma unroll
      for (int j = 0; j < 4; ++j)
        acc[i][j] = __builtin_amdgcn_mfma_f32_16x16x32_bf16(af[i], bf[j], acc[i][j], 0, 0, 0);
    __syncthreads();
  }

  // C/D layout: col = lane&15, row = quad*4 + reg
  const int r0 = bm + waveR * 64 + quad * 4;
  const int c0 = bn + waveC * 64 + l15;

  if constexpr (EPI == EPI_SCORE) {
    // raw scores * scale, bf16 store; mask applied later in softmax
    unsigned short* Cz = (unsigned short*)Cv + (long long)z * cBatch;
#pragma unroll
    for (int i = 0; i < 4; ++i)
#pragma unroll
      for (int r = 0; r < 4; ++r) {
        int row = r0 + i * 16 + r;
#pragma unroll
        for (int j = 0; j < 4; ++j) {
          int col = c0 + j * 16;
          Cz[(size_t)row * ldc + col] = f2b(acc[i][j][r] * scale);
        }
      }
  } else if constexpr (EPI == EPI_OUT) {
    float* Cz = (float*)Cv + (long long)z * cBatch;
#pragma unroll
    for (int i = 0; i < 4; ++i)
#pragma unroll
      for (int r = 0; r < 4; ++r) {
        int row = r0 + i * 16 + r;
#pragma unroll
        for (int j = 0; j < 4; ++j) {
          int col = c0 + j * 16;
          Cz[(size_t)row * ldc + col] = acc[i][j][r];
        }
      }
  } else {
    unsigned short* Cz = (unsigned short*)Cv + (long long)z * cBatch;
#pragma unroll
    for (int i = 0; i < 4; ++i)
#pragma unroll
      for (int r = 0; r < 4; ++r) {
        int row = r0 + i * 16 + r;
#pragma unroll
        for (int j = 0; j < 4; ++j) {
          int col = c0 + j * 16;
          float v = acc[i][j][r] + (EPI == EPI_BIAS_COL ? bias[col] : bias[row]);
          Cz[(size_t)row * ldc + col] = f2b(v);
        }
      }
  }
}

// ------- row softmax: bf16 scores + bitmask in -> bf16 P out ---------------
__global__ __launch_bounds__(256) void softmax_rows(const unsigned short* __restrict__ Sc,
                                                    const unsigned char* __restrict__ bits,
                                                    unsigned short* __restrict__ P) {
  const size_t r = blockIdx.x;
  const unsigned short* src = Sc + r * SS;
  unsigned short* dst = P + r * SS;
  const int tid = threadIdx.x;
  const int wave = tid >> 6, lane = tid & 63;
  union { unsigned short us[8]; uint4 v; } in;
  in.v = *(const uint4*)(src + tid * 8);
  const unsigned mb = bits[r * 256 + tid];
  float xs[8];
#pragma unroll
  for (int k = 0; k < 8; ++k)
    xs[k] = ((mb >> k) & 1u) ? -1.0e9f : b2f(in.us[k]);
  float mx = xs[0];
#pragma unroll
  for (int k = 1; k < 8; ++k) mx = fmaxf(mx, xs[k]);
#pragma unroll
  for (int o = 32; o; o >>= 1) mx = fmaxf(mx, __shfl_xor(mx, o));
  __shared__ float red[8];
  if (lane == 0) red[wave] = mx;
  __syncthreads();
  mx = fmaxf(fmaxf(red[0], red[1]), fmaxf(red[2], red[3]));
  float e[8], s = 0.f;
#pragma unroll
  for (int k = 0; k < 8; ++k) { e[k] = __expf(xs[k] - mx); s += e[k]; }
#pragma unroll
  for (int o = 32; o; o >>= 1) s += __shfl_xor(s, o);
  if (lane == 0) red[4 + wave] = s;
  __syncthreads();
  s = (red[4] + red[5]) + (red[6] + red[7]);
  float inv = 1.0f / s;
  union { unsigned short us[8]; uint4 v; } o;
#pragma unroll
  for (int k = 0; k < 8; ++k) o.us[k] = f2b(e[k] * inv);
  *(uint4*)(dst + tid * 8) = o.v;
}

extern "C" void kernel_launch(void* const* d_in, const int* in_sizes, int n_in,
                              void* d_out, int out_size, void* d_ws, size_t ws_size,
                              hipStream_t stream) {
  const float* query = (const float*)d_in[0];
  const float* key   = (const float*)d_in[1];
  const float* value = (const float*)d_in[2];
  const void*  mask  = d_in[3];                 // bool: u8 or i32, probed at runtime
  const float* Wq = (const float*)d_in[4];
  const float* bq = (const float*)d_in[5];
  const float* Wk = (const float*)d_in[6];
  const float* bk = (const float*)d_in[7];
  const float* Wv = (const float*)d_in[8];
  const float* bv = (const float*)d_in[9];
  float* out = (float*)d_out;

  char* ws = (char*)d_ws;
  const size_t MB = 1024 * 1024;
  unsigned short* qin = (unsigned short*)(ws + 0 * MB);    // 8192x1024 bf16, 16MB
  unsigned short* kin = (unsigned short*)(ws + 16 * MB);
  unsigned short* vin = (unsigned short*)(ws + 32 * MB);
  unsigned short* Wqb = (unsigned short*)(ws + 48 * MB);   // 1024x1024 bf16, 2MB
  unsigned short* Wkb = (unsigned short*)(ws + 50 * MB);
  unsigned short* Wvb = (unsigned short*)(ws + 52 * MB);
  unsigned short* qb  = (unsigned short*)(ws + 54 * MB);   // q proj bf16, 16MB
  unsigned short* kb  = (unsigned short*)(ws + 70 * MB);   // k proj
  unsigned short* vT  = (unsigned short*)(ws + 86 * MB);   // v^T [1024][8192] bf16
  unsigned short* Sc  = (unsigned short*)(ws + 102 * MB);  // scores bf16, 32MB
  unsigned short* P   = (unsigned short*)(ws + 134 * MB);  // softmax bf16, 32MB
  unsigned char*  bits= (unsigned char*)(ws + 166 * MB);   // mask bits, 2MB
  int*            flag= (int*)(ws + 168 * MB);             // mask dtype flag

  dim3 blk(256);

  detect_mask<<<dim3(1), dim3(64), 0, stream>>>((const unsigned int*)mask, flag);
  pack_mask<<<dim3(BB * SS), blk, 0, stream>>>(mask, flag, bits);

  // fp32 -> bf16
  cvt3<<<dim3(4096, 1, 3), blk, 0, stream>>>(query, key, value, qin, kin, vin);
  cvt3<<<dim3(512, 1, 3), blk, 0, stream>>>(Wq, Wk, Wv, Wqb, Wkb, Wvb);

  // q = query @ Wq^T + bq ; k = key @ Wk^T + bk   (bf16 out)
  gemm_bt<EPI_BIAS_COL><<<dim3(64, 8, 1), blk, 0, stream>>>(
      qin, 1024, 0, Wqb, 1024, 0, qb, 1024, 0, 1024, bq, 0.f);
  gemm_bt<EPI_BIAS_COL><<<dim3(64, 8, 1), blk, 0, stream>>>(
      kin, 1024, 0, Wkb, 1024, 0, kb, 1024, 0, 1024, bk, 0.f);

  // v^T[n][m] = sum_d Wv[n,d] * value[m,d] + bv[n]  -> [1024][8192] bf16
  gemm_bt<EPI_BIAS_ROW><<<dim3(8, 64, 1), blk, 0, stream>>>(
      Wvb, 1024, 0, vin, 1024, 0, vT, 8192, 0, 1024, bv, 0.f);

  // scores[b][m][n] = (q_m . k_n) / 32   (bf16, unmasked)
  gemm_bt<EPI_SCORE><<<dim3(16, 16, BB), blk, 0, stream>>>(
      qb, 1024, (long long)SS * 1024, kb, 1024, (long long)SS * 1024,
      Sc, SS, (long long)SS * SS, 1024, nullptr, 0.03125f);

  // P = softmax(mask ? -1e9 : scores) rows, bf16
  softmax_rows<<<dim3(BB * SS), blk, 0, stream>>>(Sc, bits, P);

  // out[b][m][n] = sum_k P[m][k] * vT[n][k]   (fp32 out)
  gemm_bt<EPI_OUT><<<dim3(16, 8, BB), blk, 0, stream>>>(
      P, SS, (long long)SS * SS, vT, 8192, (long long)SS,
      out, 1024, (long long)SS * 1024, SS, nullptr, 1.f);
}

// Round 5
// 374.294 us; speedup vs baseline: 1.1561x; 1.0626x over previous
//
#include <hip/hip_runtime.h>

// Problem constants
#define BB 4
#define SS 2048
#define DD 1024   // DIM_IN = DIM_Q = DIM_V = 1024

typedef __attribute__((ext_vector_type(8))) short short8;
typedef __attribute__((ext_vector_type(4))) float f32x4;

__device__ __forceinline__ unsigned short f2b(float f) {
  unsigned u = __builtin_bit_cast(unsigned, f);
  u += 0x7fffu + ((u >> 16) & 1u);   // RNE
  return (unsigned short)(u >> 16);
}
__device__ __forceinline__ float b2f(unsigned short us) {
  unsigned u = (unsigned)us << 16;
  return __builtin_bit_cast(float, u);
}

__device__ __forceinline__ void gl2lds16(const void* g, void* l) {
  __builtin_amdgcn_global_load_lds(
      (__attribute__((address_space(1))) unsigned int*)(void*)(size_t)(uintptr_t)g,
      (__attribute__((address_space(3))) unsigned int*)l, 16, 0, 0);
}

// -------- fp32 -> bf16 convert for 3 inputs (x<4096) and 3 weights (x>=4096)
__global__ __launch_bounds__(256) void cvt_all(
    const float* __restrict__ q, const float* __restrict__ k, const float* __restrict__ v,
    const float* __restrict__ wq, const float* __restrict__ wk, const float* __restrict__ wv,
    unsigned short* __restrict__ qo, unsigned short* __restrict__ ko, unsigned short* __restrict__ vo,
    unsigned short* __restrict__ wqo, unsigned short* __restrict__ wko, unsigned short* __restrict__ wvo) {
  const int z = blockIdx.z;
  const float* s;
  unsigned short* d;
  size_t i;
  if (blockIdx.x < 4096) {
    s = z == 0 ? q : (z == 1 ? k : v);
    d = z == 0 ? qo : (z == 1 ? ko : vo);
    i = (size_t)blockIdx.x * 2048 + threadIdx.x * 8;
  } else {
    s = z == 0 ? wq : (z == 1 ? wk : wv);
    d = z == 0 ? wqo : (z == 1 ? wko : wvo);
    i = (size_t)(blockIdx.x - 4096) * 2048 + threadIdx.x * 8;
  }
  float4 a = *(const float4*)(s + i);
  float4 b = *(const float4*)(s + i + 4);
  union { unsigned short us[8]; uint4 v4; } o;
  o.us[0] = f2b(a.x); o.us[1] = f2b(a.y); o.us[2] = f2b(a.z); o.us[3] = f2b(a.w);
  o.us[4] = f2b(b.x); o.us[5] = f2b(b.y); o.us[6] = f2b(b.z); o.us[7] = f2b(b.w);
  *(uint4*)(d + i) = o.v4;
}

// ---------------- BT-layout bf16 GEMM: C[m][n] = sum_k A[m][k]*B[n][k] -----
// 128x128 tile, BK=32, 256 threads (4 waves, each 64x64 via 4x4 MFMA 16x16x32)
enum { EPI_BIAS_COL = 0, EPI_BIAS_ROW = 1, EPI_SCORE = 2, EPI_OUT = 3 };

template <int EPI>
__global__ __launch_bounds__(256, 4) void gemm_bt(
    const unsigned short* __restrict__ A, int lda, long long aBatch,
    const unsigned short* __restrict__ Bm, int ldb, long long bBatch,
    void* __restrict__ Cv, int ldc, long long cBatch,
    int K,
    const float* __restrict__ bias,   // z==0 bias (or the only one)
    const float* __restrict__ bias2,  // z==1 bias for batched q/k dispatch
    float scale) {
  __shared__ unsigned short sA[128 * 32];
  __shared__ unsigned short sB[128 * 32];
  const int tid  = threadIdx.x;
  const int wave = tid >> 6;
  const int lane = tid & 63;
  const int l15  = lane & 15;
  const int quad = lane >> 4;
  const int waveR = wave >> 1, waveC = wave & 1;
  const int bm = blockIdx.x * 128;
  const int bn = blockIdx.y * 128;
  const int z  = blockIdx.z;
  A  += (long long)z * aBatch;
  Bm += (long long)z * bBatch;

  const unsigned short* gA0 = A  + (size_t)(bm + (tid >> 2)) * lda + (tid & 3) * 8;
  const unsigned short* gA1 = gA0 + (size_t)64 * lda;
  const unsigned short* gB0 = Bm + (size_t)(bn + (tid >> 2)) * ldb + (tid & 3) * 8;
  const unsigned short* gB1 = gB0 + (size_t)64 * ldb;
  unsigned short* lA = sA + wave * 64 * 8;   // wave-uniform LDS base; HW adds lane*16B
  unsigned short* lB = sB + wave * 64 * 8;

  f32x4 acc[4][4] = {};

  const int aro = (waveR * 64 + l15) * 32 + quad * 8;
  const int bro = (waveC * 64 + l15) * 32 + quad * 8;

  for (int kt = 0; kt < K; kt += 32) {
    gl2lds16(gA0, lA);
    gl2lds16(gA1, lA + 256 * 8);
    gl2lds16(gB0, lB);
    gl2lds16(gB1, lB + 256 * 8);
    gA0 += 32; gA1 += 32; gB0 += 32; gB1 += 32;
    __syncthreads();
    short8 af[4], bf[4];
#pragma unroll
    for (int i = 0; i < 4; ++i) af[i] = *(const short8*)(sA + aro + i * 16 * 32);
#pragma unroll
    for (int j = 0; j < 4; ++j) bf[j] = *(const short8*)(sB + bro + j * 16 * 32);
#pragma unroll
    for (int i = 0; i < 4; ++i)
#pragma unroll
      for (int j = 0; j < 4; ++j)
        acc[i][j] = __builtin_amdgcn_mfma_f32_16x16x32_bf16(af[i], bf[j], acc[i][j], 0, 0, 0);
    __syncthreads();
  }

  // C/D layout: col = lane&15, row = quad*4 + reg
  const int r0 = bm + waveR * 64 + quad * 4;
  const int c0 = bn + waveC * 64 + l15;

  if constexpr (EPI == EPI_SCORE) {
    unsigned short* Cz = (unsigned short*)Cv + (long long)z * cBatch;
#pragma unroll
    for (int i = 0; i < 4; ++i)
#pragma unroll
      for (int r = 0; r < 4; ++r) {
        int row = r0 + i * 16 + r;
#pragma unroll
        for (int j = 0; j < 4; ++j) {
          int col = c0 + j * 16;
          Cz[(size_t)row * ldc + col] = f2b(acc[i][j][r] * scale);
        }
      }
  } else if constexpr (EPI == EPI_OUT) {
    float* Cz = (float*)Cv + (long long)z * cBatch;
#pragma unroll
    for (int i = 0; i < 4; ++i)
#pragma unroll
      for (int r = 0; r < 4; ++r) {
        int row = r0 + i * 16 + r;
#pragma unroll
        for (int j = 0; j < 4; ++j) {
          int col = c0 + j * 16;
          Cz[(size_t)row * ldc + col] = acc[i][j][r];
        }
      }
  } else {
    const float* bp = (z == 0) ? bias : bias2;
    unsigned short* Cz = (unsigned short*)Cv + (long long)z * cBatch;
#pragma unroll
    for (int i = 0; i < 4; ++i)
#pragma unroll
      for (int r = 0; r < 4; ++r) {
        int row = r0 + i * 16 + r;
#pragma unroll
        for (int j = 0; j < 4; ++j) {
          int col = c0 + j * 16;
          float v = acc[i][j][r] + (EPI == EPI_BIAS_COL ? bp[col] : bp[row]);
          Cz[(size_t)row * ldc + col] = f2b(v);
        }
      }
  }
}

// ------- row softmax: bf16 scores + raw mask (dtype self-probed) -> bf16 P --
__global__ __launch_bounds__(256) void softmax_rows(const unsigned short* __restrict__ Sc,
                                                    const void* __restrict__ mask,
                                                    unsigned short* __restrict__ P) {
  const size_t r = blockIdx.x;
  const unsigned short* src = Sc + r * SS;
  unsigned short* dst = P + r * SS;
  const int tid = threadIdx.x;
  const int wave = tid >> 6, lane = tid & 63;
  __shared__ int anyv[4];
  __shared__ float red[8];

  // dtype probe: first 256 words are inside row 0 for both layouts.
  // i32 bools -> all words 0/1. u8 packed bools -> word >1 w.p. 7/8.
  unsigned pw = ((const unsigned*)mask)[tid];
  unsigned long long bal = __ballot(pw > 1u);
  if (lane == 0) anyv[wave] = (bal != 0ULL) ? 1 : 0;
  __syncthreads();
  const bool isU8 = (anyv[0] | anyv[1] | anyv[2] | anyv[3]) != 0;

  // mask bits for cols [tid*8, tid*8+8)
  unsigned mbits = 0;
  if (isU8) {
    uint2 v = *(const uint2*)((const unsigned char*)mask + r * SS + tid * 8);
#pragma unroll
    for (int j = 0; j < 4; ++j) {
      mbits |= (((v.x >> (8 * j)) & 0xffu) ? 1u : 0u) << j;
      mbits |= (((v.y >> (8 * j)) & 0xffu) ? 1u : 0u) << (j + 4);
    }
  } else {
    const uint4* p = (const uint4*)((const int*)mask + r * SS + tid * 8);
    uint4 a = p[0], b = p[1];
    mbits = (a.x ? 1u : 0u) | ((a.y ? 1u : 0u) << 1) | ((a.z ? 1u : 0u) << 2) |
            ((a.w ? 1u : 0u) << 3) | ((b.x ? 1u : 0u) << 4) | ((b.y ? 1u : 0u) << 5) |
            ((b.z ? 1u : 0u) << 6) | ((b.w ? 1u : 0u) << 7);
  }

  union { unsigned short us[8]; uint4 v; } in;
  in.v = *(const uint4*)(src + tid * 8);
  float xs[8];
#pragma unroll
  for (int k = 0; k < 8; ++k)
    xs[k] = ((mbits >> k) & 1u) ? -1.0e9f : b2f(in.us[k]);
  float mx = xs[0];
#pragma unroll
  for (int k = 1; k < 8; ++k) mx = fmaxf(mx, xs[k]);
#pragma unroll
  for (int o = 32; o; o >>= 1) mx = fmaxf(mx, __shfl_xor(mx, o));
  if (lane == 0) red[wave] = mx;
  __syncthreads();
  mx = fmaxf(fmaxf(red[0], red[1]), fmaxf(red[2], red[3]));
  float e[8], s = 0.f;
#pragma unroll
  for (int k = 0; k < 8; ++k) { e[k] = __expf(xs[k] - mx); s += e[k]; }
#pragma unroll
  for (int o = 32; o; o >>= 1) s += __shfl_xor(s, o);
  if (lane == 0) red[4 + wave] = s;
  __syncthreads();
  s = (red[4] + red[5]) + (red[6] + red[7]);
  float inv = 1.0f / s;
  union { unsigned short us[8]; uint4 v; } o;
#pragma unroll
  for (int k = 0; k < 8; ++k) o.us[k] = f2b(e[k] * inv);
  *(uint4*)(dst + tid * 8) = o.v;
}

extern "C" void kernel_launch(void* const* d_in, const int* in_sizes, int n_in,
                              void* d_out, int out_size, void* d_ws, size_t ws_size,
                              hipStream_t stream) {
  const float* query = (const float*)d_in[0];
  const float* key   = (const float*)d_in[1];
  const float* value = (const float*)d_in[2];
  const void*  mask  = d_in[3];                 // bool: u8 or i32, self-probed
  const float* Wq = (const float*)d_in[4];
  const float* bq = (const float*)d_in[5];
  const float* Wk = (const float*)d_in[6];
  const float* bk = (const float*)d_in[7];
  const float* Wv = (const float*)d_in[8];
  const float* bv = (const float*)d_in[9];
  float* out = (float*)d_out;

  char* ws = (char*)d_ws;
  const size_t MB = 1024 * 1024;
  unsigned short* qin = (unsigned short*)(ws + 0 * MB);    // 8192x1024 bf16, 16MB
  unsigned short* kin = (unsigned short*)(ws + 16 * MB);   // (qin+z*8M for z batching)
  unsigned short* vin = (unsigned short*)(ws + 32 * MB);
  unsigned short* Wqb = (unsigned short*)(ws + 48 * MB);   // 1024x1024 bf16, 2MB
  unsigned short* Wkb = (unsigned short*)(ws + 50 * MB);   // (Wqb+z*1M)
  unsigned short* Wvb = (unsigned short*)(ws + 52 * MB);
  unsigned short* qb  = (unsigned short*)(ws + 54 * MB);   // q proj bf16, 16MB
  unsigned short* kb  = (unsigned short*)(ws + 70 * MB);   // (qb+z*8M)
  unsigned short* vT  = (unsigned short*)(ws + 86 * MB);   // v^T [1024][8192] bf16
  unsigned short* Sc  = (unsigned short*)(ws + 102 * MB);  // scores bf16, 32MB
  unsigned short* P   = (unsigned short*)(ws + 134 * MB);  // softmax bf16, 32MB

  dim3 blk(256);

  // fp32 -> bf16 for all six tensors (one dispatch)
  cvt_all<<<dim3(4608, 1, 3), blk, 0, stream>>>(
      query, key, value, Wq, Wk, Wv, qin, kin, vin, Wqb, Wkb, Wvb);

  // q = query @ Wq^T + bq ; k = key @ Wk^T + bk   (batched z=2, bf16 out)
  gemm_bt<EPI_BIAS_COL><<<dim3(64, 8, 2), blk, 0, stream>>>(
      qin, 1024, 8388608LL, Wqb, 1024, 1048576LL, qb, 1024, 8388608LL,
      1024, bq, bk, 0.f);

  // v^T[n][m] = sum_d Wv[n,d] * value[m,d] + bv[n]  -> [1024][8192] bf16
  gemm_bt<EPI_BIAS_ROW><<<dim3(8, 64, 1), blk, 0, stream>>>(
      Wvb, 1024, 0, vin, 1024, 0, vT, 8192, 0, 1024, bv, bv, 0.f);

  // scores[b][m][n] = (q_m . k_n) / 32   (bf16, unmasked)
  gemm_bt<EPI_SCORE><<<dim3(16, 16, BB), blk, 0, stream>>>(
      qb, 1024, (long long)SS * 1024, kb, 1024, (long long)SS * 1024,
      Sc, SS, (long long)SS * SS, 1024, nullptr, nullptr, 0.03125f);

  // P = softmax(mask ? -1e9 : scores) rows, bf16
  softmax_rows<<<dim3(BB * SS), blk, 0, stream>>>(Sc, mask, P);

  // out[b][m][n] = sum_k P[m][k] * vT[n][k]   (fp32 out)
  gemm_bt<EPI_OUT><<<dim3(16, 8, BB), blk, 0, stream>>>(
      P, SS, (long long)SS * SS, vT, 8192, (long long)SS,
      out, 1024, (long long)SS * 1024, SS, nullptr, nullptr, 1.f);
}

// Round 7
// 374.204 us; speedup vs baseline: 1.1563x; 1.0002x over previous
//
#include <hip/hip_runtime.h>

// Problem constants
#define BB 4
#define SS 2048
#define DD 1024   // DIM_IN = DIM_Q = DIM_V = 1024

typedef __attribute__((ext_vector_type(8))) short short8;
typedef __attribute__((ext_vector_type(4))) float f32x4;

__device__ __forceinline__ unsigned short f2b(float f) {
  unsigned u = __builtin_bit_cast(unsigned, f);
  u += 0x7fffu + ((u >> 16) & 1u);   // RNE
  return (unsigned short)(u >> 16);
}
__device__ __forceinline__ float b2f(unsigned short us) {
  unsigned u = (unsigned)us << 16;
  return __builtin_bit_cast(float, u);
}

__device__ __forceinline__ void gl2lds16(const void* g, void* l) {
  __builtin_amdgcn_global_load_lds(
      (__attribute__((address_space(1))) unsigned int*)(void*)(size_t)(uintptr_t)g,
      (__attribute__((address_space(3))) unsigned int*)l, 16, 0, 0);
}

// -------- fp32 -> bf16 convert for 3 inputs (x<4096) and 3 weights (x>=4096)
__global__ __launch_bounds__(256) void cvt_all(
    const float* __restrict__ q, const float* __restrict__ k, const float* __restrict__ v,
    const float* __restrict__ wq, const float* __restrict__ wk, const float* __restrict__ wv,
    unsigned short* __restrict__ qo, unsigned short* __restrict__ ko, unsigned short* __restrict__ vo,
    unsigned short* __restrict__ wqo, unsigned short* __restrict__ wko, unsigned short* __restrict__ wvo) {
  const int z = blockIdx.z;
  const float* s;
  unsigned short* d;
  size_t i;
  if (blockIdx.x < 4096) {
    s = z == 0 ? q : (z == 1 ? k : v);
    d = z == 0 ? qo : (z == 1 ? ko : vo);
    i = (size_t)blockIdx.x * 2048 + threadIdx.x * 8;
  } else {
    s = z == 0 ? wq : (z == 1 ? wk : wv);
    d = z == 0 ? wqo : (z == 1 ? wko : wvo);
    i = (size_t)(blockIdx.x - 4096) * 2048 + threadIdx.x * 8;
  }
  float4 a = *(const float4*)(s + i);
  float4 b = *(const float4*)(s + i + 4);
  union { unsigned short us[8]; uint4 v4; } o;
  o.us[0] = f2b(a.x); o.us[1] = f2b(a.y); o.us[2] = f2b(a.z); o.us[3] = f2b(a.w);
  o.us[4] = f2b(b.x); o.us[5] = f2b(b.y); o.us[6] = f2b(b.z); o.us[7] = f2b(b.w);
  *(uint4*)(d + i) = o.v4;
}

// ---------------- BT-layout bf16 GEMM: C[m][n] = sum_k A[m][k]*B[n][k] -----
// 128x128 tile, BK=32, 256 threads (4 waves, each 64x64 via 4x4 MFMA 16x16x32)
enum { EPI_BIAS_COL = 0, EPI_BIAS_ROW = 1, EPI_SCORE = 2, EPI_OUT = 3 };

// __launch_bounds__(256,2): round4<->5 A/B showed (256,4) regresses the
// scores GEMM 55.8 -> 59.2 us with no occupancy gain. Keep 2.
template <int EPI>
__global__ __launch_bounds__(256, 2) void gemm_bt(
    const unsigned short* __restrict__ A, int lda, long long aBatch,
    const unsigned short* __restrict__ Bm, int ldb, long long bBatch,
    void* __restrict__ Cv, int ldc, long long cBatch,
    int K,
    const float* __restrict__ bias,   // z==0 bias (or the only one)
    const float* __restrict__ bias2,  // z==1 bias for batched q/k dispatch
    float scale) {
  __shared__ unsigned short sA[128 * 32];
  __shared__ unsigned short sB[128 * 32];
  const int tid  = threadIdx.x;
  const int wave = tid >> 6;
  const int lane = tid & 63;
  const int l15  = lane & 15;
  const int quad = lane >> 4;
  const int waveR = wave >> 1, waveC = wave & 1;
  const int bm = blockIdx.x * 128;
  const int bn = blockIdx.y * 128;
  const int z  = blockIdx.z;
  A  += (long long)z * aBatch;
  Bm += (long long)z * bBatch;

  const unsigned short* gA0 = A  + (size_t)(bm + (tid >> 2)) * lda + (tid & 3) * 8;
  const unsigned short* gA1 = gA0 + (size_t)64 * lda;
  const unsigned short* gB0 = Bm + (size_t)(bn + (tid >> 2)) * ldb + (tid & 3) * 8;
  const unsigned short* gB1 = gB0 + (size_t)64 * ldb;
  unsigned short* lA = sA + wave * 64 * 8;   // wave-uniform LDS base; HW adds lane*16B
  unsigned short* lB = sB + wave * 64 * 8;

  f32x4 acc[4][4] = {};

  const int aro = (waveR * 64 + l15) * 32 + quad * 8;
  const int bro = (waveC * 64 + l15) * 32 + quad * 8;

  for (int kt = 0; kt < K; kt += 32) {
    gl2lds16(gA0, lA);
    gl2lds16(gA1, lA + 256 * 8);
    gl2lds16(gB0, lB);
    gl2lds16(gB1, lB + 256 * 8);
    gA0 += 32; gA1 += 32; gB0 += 32; gB1 += 32;
    __syncthreads();
    short8 af[4], bf[4];
#pragma unroll
    for (int i = 0; i < 4; ++i) af[i] = *(const short8*)(sA + aro + i * 16 * 32);
#pragma unroll
    for (int j = 0; j < 4; ++j) bf[j] = *(const short8*)(sB + bro + j * 16 * 32);
#pragma unroll
    for (int i = 0; i < 4; ++i)
#pragma unroll
      for (int j = 0; j < 4; ++j)
        acc[i][j] = __builtin_amdgcn_mfma_f32_16x16x32_bf16(af[i], bf[j], acc[i][j], 0, 0, 0);
    __syncthreads();
  }

  // C/D layout: col = lane&15, row = quad*4 + reg
  const int r0 = bm + waveR * 64 + quad * 4;
  const int c0 = bn + waveC * 64 + l15;

  if constexpr (EPI == EPI_SCORE) {
    unsigned short* Cz = (unsigned short*)Cv + (long long)z * cBatch;
#pragma unroll
    for (int i = 0; i < 4; ++i)
#pragma unroll
      for (int r = 0; r < 4; ++r) {
        int row = r0 + i * 16 + r;
#pragma unroll
        for (int j = 0; j < 4; ++j) {
          int col = c0 + j * 16;
          Cz[(size_t)row * ldc + col] = f2b(acc[i][j][r] * scale);
        }
      }
  } else if constexpr (EPI == EPI_OUT) {
    float* Cz = (float*)Cv + (long long)z * cBatch;
#pragma unroll
    for (int i = 0; i < 4; ++i)
#pragma unroll
      for (int r = 0; r < 4; ++r) {
        int row = r0 + i * 16 + r;
#pragma unroll
        for (int j = 0; j < 4; ++j) {
          int col = c0 + j * 16;
          Cz[(size_t)row * ldc + col] = acc[i][j][r];
        }
      }
  } else {
    const float* bp = (z == 0) ? bias : bias2;
    unsigned short* Cz = (unsigned short*)Cv + (long long)z * cBatch;
#pragma unroll
    for (int i = 0; i < 4; ++i)
#pragma unroll
      for (int r = 0; r < 4; ++r) {
        int row = r0 + i * 16 + r;
#pragma unroll
        for (int j = 0; j < 4; ++j) {
          int col = c0 + j * 16;
          float v = acc[i][j][r] + (EPI == EPI_BIAS_COL ? bp[col] : bp[row]);
          Cz[(size_t)row * ldc + col] = f2b(v);
        }
      }
  }
}

// ------- row softmax: bf16 scores + raw mask (dtype self-probed) -> bf16 P --
__global__ __launch_bounds__(256) void softmax_rows(const unsigned short* __restrict__ Sc,
                                                    const void* __restrict__ mask,
                                                    unsigned short* __restrict__ P) {
  const size_t r = blockIdx.x;
  const unsigned short* src = Sc + r * SS;
  unsigned short* dst = P + r * SS;
  const int tid = threadIdx.x;
  const int wave = tid >> 6, lane = tid & 63;
  __shared__ int anyv[4];
  __shared__ float red[8];

  // dtype probe: first 256 words are inside row 0 for both layouts.
  // i32 bools -> all words 0/1. u8 packed bools -> word >1 w.p. 7/8.
  unsigned pw = ((const unsigned*)mask)[tid];
  unsigned long long bal = __ballot(pw > 1u);
  if (lane == 0) anyv[wave] = (bal != 0ULL) ? 1 : 0;
  __syncthreads();
  const bool isU8 = (anyv[0] | anyv[1] | anyv[2] | anyv[3]) != 0;

  // mask bits for cols [tid*8, tid*8+8)
  unsigned mbits = 0;
  if (isU8) {
    uint2 v = *(const uint2*)((const unsigned char*)mask + r * SS + tid * 8);
#pragma unroll
    for (int j = 0; j < 4; ++j) {
      mbits |= (((v.x >> (8 * j)) & 0xffu) ? 1u : 0u) << j;
      mbits |= (((v.y >> (8 * j)) & 0xffu) ? 1u : 0u) << (j + 4);
    }
  } else {
    const uint4* p = (const uint4*)((const int*)mask + r * SS + tid * 8);
    uint4 a = p[0], b = p[1];
    mbits = (a.x ? 1u : 0u) | ((a.y ? 1u : 0u) << 1) | ((a.z ? 1u : 0u) << 2) |
            ((a.w ? 1u : 0u) << 3) | ((b.x ? 1u : 0u) << 4) | ((b.y ? 1u : 0u) << 5) |
            ((b.z ? 1u : 0u) << 6) | ((b.w ? 1u : 0u) << 7);
  }

  union { unsigned short us[8]; uint4 v; } in;
  in.v = *(const uint4*)(src + tid * 8);
  float xs[8];
#pragma unroll
  for (int k = 0; k < 8; ++k)
    xs[k] = ((mbits >> k) & 1u) ? -1.0e9f : b2f(in.us[k]);
  float mx = xs[0];
#pragma unroll
  for (int k = 1; k < 8; ++k) mx = fmaxf(mx, xs[k]);
#pragma unroll
  for (int o = 32; o; o >>= 1) mx = fmaxf(mx, __shfl_xor(mx, o));
  if (lane == 0) red[wave] = mx;
  __syncthreads();
  mx = fmaxf(fmaxf(red[0], red[1]), fmaxf(red[2], red[3]));
  float e[8], s = 0.f;
#pragma unroll
  for (int k = 0; k < 8; ++k) { e[k] = __expf(xs[k] - mx); s += e[k]; }
#pragma unroll
  for (int o = 32; o; o >>= 1) s += __shfl_xor(s, o);
  if (lane == 0) red[4 + wave] = s;
  __syncthreads();
  s = (red[4] + red[5]) + (red[6] + red[7]);
  float inv = 1.0f / s;
  union { unsigned short us[8]; uint4 v; } o;
#pragma unroll
  for (int k = 0; k < 8; ++k) o.us[k] = f2b(e[k] * inv);
  *(uint4*)(dst + tid * 8) = o.v;
}

extern "C" void kernel_launch(void* const* d_in, const int* in_sizes, int n_in,
                              void* d_out, int out_size, void* d_ws, size_t ws_size,
                              hipStream_t stream) {
  const float* query = (const float*)d_in[0];
  const float* key   = (const float*)d_in[1];
  const float* value = (const float*)d_in[2];
  const void*  mask  = d_in[3];                 // bool: u8 or i32, self-probed
  const float* Wq = (const float*)d_in[4];
  const float* bq = (const float*)d_in[5];
  const float* Wk = (const float*)d_in[6];
  const float* bk = (const float*)d_in[7];
  const float* Wv = (const float*)d_in[8];
  const float* bv = (const float*)d_in[9];
  float* out = (float*)d_out;

  char* ws = (char*)d_ws;
  const size_t MB = 1024 * 1024;
  unsigned short* qin = (unsigned short*)(ws + 0 * MB);    // 8192x1024 bf16, 16MB
  unsigned short* kin = (unsigned short*)(ws + 16 * MB);   // (qin+z*8M for z batching)
  unsigned short* vin = (unsigned short*)(ws + 32 * MB);
  unsigned short* Wqb = (unsigned short*)(ws + 48 * MB);   // 1024x1024 bf16, 2MB
  unsigned short* Wkb = (unsigned short*)(ws + 50 * MB);   // (Wqb+z*1M)
  unsigned short* Wvb = (unsigned short*)(ws + 52 * MB);
  unsigned short* qb  = (unsigned short*)(ws + 54 * MB);   // q proj bf16, 16MB
  unsigned short* kb  = (unsigned short*)(ws + 70 * MB);   // (qb+z*8M)
  unsigned short* vT  = (unsigned short*)(ws + 86 * MB);   // v^T [1024][8192] bf16
  unsigned short* Sc  = (unsigned short*)(ws + 102 * MB);  // scores bf16, 32MB
  unsigned short* P   = (unsigned short*)(ws + 134 * MB);  // softmax bf16, 32MB

  dim3 blk(256);

  // fp32 -> bf16 for all six tensors (one dispatch)
  cvt_all<<<dim3(4608, 1, 3), blk, 0, stream>>>(
      query, key, value, Wq, Wk, Wv, qin, kin, vin, Wqb, Wkb, Wvb);

  // q = query @ Wq^T + bq ; k = key @ Wk^T + bk   (batched z=2, bf16 out)
  gemm_bt<EPI_BIAS_COL><<<dim3(64, 8, 2), blk, 0, stream>>>(
      qin, 1024, 8388608LL, Wqb, 1024, 1048576LL, qb, 1024, 8388608LL,
      1024, bq, bk, 0.f);

  // v^T[n][m] = sum_d Wv[n,d] * value[m,d] + bv[n]  -> [1024][8192] bf16
  gemm_bt<EPI_BIAS_ROW><<<dim3(8, 64, 1), blk, 0, stream>>>(
      Wvb, 1024, 0, vin, 1024, 0, vT, 8192, 0, 1024, bv, bv, 0.f);

  // scores[b][m][n] = (q_m . k_n) / 32   (bf16, unmasked)
  gemm_bt<EPI_SCORE><<<dim3(16, 16, BB), blk, 0, stream>>>(
      qb, 1024, (long long)SS * 1024, kb, 1024, (long long)SS * 1024,
      Sc, SS, (long long)SS * SS, 1024, nullptr, nullptr, 0.03125f);

  // P = softmax(mask ? -1e9 : scores) rows, bf16
  softmax_rows<<<dim3(BB * SS), blk, 0, stream>>>(Sc, mask, P);

  // out[b][m][n] = sum_k P[m][k] * vT[n][k]   (fp32 out)
  gemm_bt<EPI_OUT><<<dim3(16, 8, BB), blk, 0, stream>>>(
      P, SS, (long long)SS * SS, vT, 8192, (long long)SS,
      out, 1024, (long long)SS * 1024, SS, nullptr, nullptr, 1.f);
}